// Round 9
// baseline (699.420 us; speedup 1.0000x reference)
//
#include <hip/hip_runtime.h>
#include <hip/hip_bf16.h>

// Problem constants
#define PB 4
#define PN 2048
#define PD 1024
#define PH 16
#define PHD 64
#define NSC 11

typedef __attribute__((ext_vector_type(8))) short short8;
typedef __attribute__((ext_vector_type(4))) float floatx4;

#define AS1 __attribute__((address_space(1)))
#define AS3 __attribute__((address_space(3)))

static __device__ __forceinline__ unsigned short bf16bits(float f) {
    __hip_bfloat16 h = __float2bfloat16(f);
    return __builtin_bit_cast(unsigned short, h);
}

// ---------------- cast kernels ----------------
__global__ void cast_f32_to_bf16_v4(const float4* __restrict__ in,
                                    ushort4* __restrict__ out, int n4) {
    int i = blockIdx.x * blockDim.x + threadIdx.x;
    if (i < n4) {
        float4 v = in[i];
        ushort4 o;
        o.x = bf16bits(v.x);
        o.y = bf16bits(v.y);
        o.z = bf16bits(v.z);
        o.w = bf16bits(v.w);
        out[i] = o;
    }
}

// casts W_qkv (3M) + W_gate (1M) into wcomb, W_out (1M) into wout
__global__ void cast_weights(const float4* __restrict__ wqkv,
                             const float4* __restrict__ wgate,
                             const float4* __restrict__ wout,
                             ushort4* __restrict__ wcomb,
                             ushort4* __restrict__ woutb) {
    int i = blockIdx.x * blockDim.x + threadIdx.x;  // 0 .. 5M/4
    const int QKV4 = 3 * PD * PD / 4;
    const int G4 = PD * PD / 4;
    float4 v;
    ushort4* dst;
    if (i < QKV4) {
        v = wqkv[i];
        dst = wcomb + i;
    } else if (i < QKV4 + G4) {
        v = wgate[i - QKV4];
        dst = wcomb + i;
    } else {
        v = wout[i - QKV4 - G4];
        dst = woutb + (i - QKV4 - G4);
    }
    ushort4 o;
    o.x = bf16bits(v.x);
    o.y = bf16bits(v.y);
    o.z = bf16bits(v.z);
    o.w = bf16bits(v.w);
    *dst = o;
}

// ---------------- GEMM 128x128: C = A @ B^T + bias, dual output ----------------
// A: [M,K] bf16 row-major; Bm: [Nn,K] bf16 row-major (W[out][in]).
// Columns < split  -> out1 (row stride N1), bias b1
// Columns >= split -> out2 (row stride N2), bias b2   (split is 128-aligned,
// so the branch is block-uniform)
#define GBM 128
#define GBN 128
#define GBK 64

__global__ __launch_bounds__(256) void gemm_bt128(
    const __hip_bfloat16* __restrict__ A,
    const __hip_bfloat16* __restrict__ Bm,
    const float* __restrict__ b1,
    const float* __restrict__ b2,
    int split,
    float* __restrict__ out1, int N1,
    float* __restrict__ out2, int N2,
    int K) {
    __shared__ alignas(16) __hip_bfloat16 sA[GBM * GBK];
    __shared__ alignas(16) __hip_bfloat16 sB[GBN * GBK];

    const int tid = threadIdx.x;
    const int lane = tid & 63;
    const int wave = tid >> 6;   // 0..3
    const int wy = wave >> 1;    // 0..1
    const int wx = wave & 1;     // 0..1

    // staging: each global_load_lds covers 8 rows x 64 elems (1 KiB)
    const int lrow8 = lane >> 3;                 // 0..7
    const int lchunk = lane & 7;                 // LDS chunk slot (8 elems)
    const int gchunk = lchunk ^ lrow8;           // global chunk fetched into slot

    const int r16 = lane & 15;
    const int qd = lane >> 4;
    const int sw = r16 & 7;  // reader swizzle key

    floatx4 acc[4][4];
#pragma unroll
    for (int i = 0; i < 4; i++)
#pragma unroll
        for (int j = 0; j < 4; j++) acc[i][j] = (floatx4){0.f, 0.f, 0.f, 0.f};

    const size_t arow0 = (size_t)blockIdx.y * GBM;
    const size_t brow0 = (size_t)blockIdx.x * GBN;

    for (int k0 = 0; k0 < K; k0 += GBK) {
        __syncthreads();  // previous ds_reads done before overwrite
#pragma unroll
        for (int half = 0; half < 4; half++) {
            const int rbase = wave * 8 + half * 32;  // wave-uniform
            const __hip_bfloat16* gA =
                A + (arow0 + rbase + lrow8) * K + k0 + gchunk * 8;
            __builtin_amdgcn_global_load_lds(
                (const AS1 unsigned int*)(const void*)gA,
                (AS3 unsigned int*)(void*)(sA + rbase * GBK), 16, 0, 0);
            const __hip_bfloat16* gB =
                Bm + (brow0 + rbase + lrow8) * K + k0 + gchunk * 8;
            __builtin_amdgcn_global_load_lds(
                (const AS1 unsigned int*)(const void*)gB,
                (AS3 unsigned int*)(void*)(sB + rbase * GBK), 16, 0, 0);
        }
        __syncthreads();  // drain staging

#pragma unroll
        for (int kk = 0; kk < 2; kk++) {
            short8 af[4], bf[4];
            const int cs = (qd + 4 * kk);
#pragma unroll
            for (int i = 0; i < 4; i++)
                af[i] = *(const short8*)(sA + (wy * 64 + i * 16 + r16) * GBK +
                                         ((cs ^ sw) * 8));
#pragma unroll
            for (int j = 0; j < 4; j++)
                bf[j] = *(const short8*)(sB + (wx * 64 + j * 16 + r16) * GBK +
                                         ((cs ^ sw) * 8));
#pragma unroll
            for (int i = 0; i < 4; i++)
#pragma unroll
                for (int j = 0; j < 4; j++)
                    acc[i][j] = __builtin_amdgcn_mfma_f32_16x16x32_bf16(
                        af[i], bf[j], acc[i][j], 0, 0, 0);
        }
    }

#pragma unroll
    for (int i = 0; i < 4; i++) {
#pragma unroll
        for (int j = 0; j < 4; j++) {
            const int colb = (int)brow0 + wx * 64 + j * 16 + r16;
            const bool first = colb < split;
            const float bb = first ? b1[colb] : b2[colb - split];
            float* dst = first ? out1 : out2;
            const int nn = first ? N1 : N2;
            const int cc = first ? colb : colb - split;
#pragma unroll
            for (int e = 0; e < 4; e++) {
                const size_t row = arow0 + wy * 64 + i * 16 + qd * 4 + e;
                dst[row * (size_t)nn + cc] = acc[i][j][e] + bb;
            }
        }
    }
}

// ---------------- attention + gating kernel ----------------
// Layout: 1 wave = 4 consecutive n positions; 16 lanes x float4 per position.
// qkv: [B, N, 3D] fp32 (EXACT R6 layout); gatep: [B, N, D] fp32 (separate).
// Writes gated bf16 [B,N,D]: bf16((out/z) * sigmoid(gate_preact)).

__device__ __constant__ const int OFFS[21] = {1, 2, 3, 4, 6, 8, 12, 16, 24, 32, 48,
                                              64, 96, 128, 192, 256, 384, 512, 768, 1024, 1536};
__device__ __constant__ const int U1J[21] = {0, 0, 0, 1, 1, 2, 2, 3, 3, 4, 4,
                                             5, 5, 6, 6, 7, 7, 8, 8, 9, 9};
__device__ __constant__ const int U1T[21] = {1, 2, 3, 2, 3, 2, 3, 2, 3, 2, 3,
                                             2, 3, 2, 3, 2, 3, 2, 3, 2, 3};
// second user j (tau is always 1); -1 = none
__device__ __constant__ const int U2J[21] = {-1, 1, -1, 2, -1, 3, -1, 4, -1, 5, -1,
                                             6, -1, 7, -1, 8, -1, 9, -1, 10, -1};

static __device__ __forceinline__ float red16(float s) {
    // sum across each 16-lane DPP row via rotations; all lanes get the sum
    int t;
    t = __builtin_amdgcn_update_dpp(0, __builtin_bit_cast(int, s), 0x121, 0xF, 0xF, true);
    s += __builtin_bit_cast(float, t);  // row_ror:1
    t = __builtin_amdgcn_update_dpp(0, __builtin_bit_cast(int, s), 0x122, 0xF, 0xF, true);
    s += __builtin_bit_cast(float, t);  // row_ror:2
    t = __builtin_amdgcn_update_dpp(0, __builtin_bit_cast(int, s), 0x124, 0xF, 0xF, true);
    s += __builtin_bit_cast(float, t);  // row_ror:4
    t = __builtin_amdgcn_update_dpp(0, __builtin_bit_cast(int, s), 0x128, 0xF, 0xF, true);
    s += __builtin_bit_cast(float, t);  // row_ror:8
    return s;
}

__global__ __launch_bounds__(256, 6) void attn_kernel(
    const float* __restrict__ qkv,
    const float* __restrict__ scale_gain,       // [11,16]
    const float* __restrict__ W_qscale,         // [11,64]
    const float* __restrict__ identity_bypass,  // [16]
    const float* __restrict__ pos_bias,         // [44,16]
    const float* __restrict__ gatep,            // [B,N,D] gate preact
    __hip_bfloat16* __restrict__ gated) {
    const int lane = threadIdx.x & 63;
    const int p = lane >> 4;   // position within wave, 0..3
    const int l = lane & 15;   // d-chunk, 0..15

    const int flat = (blockIdx.x * 4 + (threadIdx.x >> 6)) * 4;  // first n of wave
    const int n = (flat & (PN - 1)) + p;
    const int h = (flat >> 11) & (PH - 1);
    const int b = flat >> 15;

    const size_t base_bn = (size_t)b * PN;
    const int col = h * PHD + l * 4;

    const float4 q4 = *(const float4*)(qkv + (base_bn + n) * (3 * PD) + col);
    const float4 k04 = *(const float4*)(qkv + (base_bn + n) * (3 * PD) + PD + col);
    const float4 v04 = *(const float4*)(qkv + (base_bn + n) * (3 * PD) + 2 * PD + col);

    auto dot16 = [](float4 a, float4 b) {
        float s = a.x * b.x;
        s = fmaf(a.y, b.y, s);
        s = fmaf(a.z, b.z, s);
        s = fmaf(a.w, b.w, s);
        return red16(s);
    };

    const float dot0 = dot16(q4, k04);

    // gains = softmax(q @ W_qscale^T + scale_gain[:,h]) over 11 scales
    float g[NSC];
    float mx = -1e30f;
#pragma unroll
    for (int s = 0; s < NSC; s++) {
        const float4 w4 = *(const float4*)(W_qscale + s * PHD + l * 4);
        g[s] = dot16(q4, w4) + scale_gain[s * PH + h];
        mx = fmaxf(mx, g[s]);
    }
    float ssum = 0.f;
#pragma unroll
    for (int s = 0; s < NSC; s++) {
        g[s] = __expf(g[s] - mx);
        ssum += g[s];
    }
    const float inv = 1.f / ssum;
#pragma unroll
    for (int s = 0; s < NSC; s++) g[s] *= inv;

    const float D4c[4] = {0.4829629131445341f, 0.8365163037378079f,
                          0.2241438680420134f, -0.1294095225512604f};

    float4 out4 = {0.f, 0.f, 0.f, 0.f};
    float z = 0.f;

    // offset-0 taps: tau=0 for every scale j
#pragma unroll
    for (int j = 0; j < NSC; j++) {
        const float xx = dot0 + pos_bias[(j * 4) * PH + h];
        const float feat = (xx > 0.f ? xx : __expf(xx) - 1.f) + 1.f;
        const float w = g[j] * D4c[0] * feat;
        out4.x = fmaf(w, v04.x, out4.x);
        out4.y = fmaf(w, v04.y, out4.y);
        out4.z = fmaf(w, v04.z, out4.z);
        out4.w = fmaf(w, v04.w, out4.w);
        z = fmaf(g[j] * D4c[0], feat, z);  // |coef| == coef for tau=0
    }

    // distinct nonzero offsets (each used by 1-2 taps)
#pragma unroll
    for (int t = 0; t < 21; t++) {
        const int off = OFFS[t];
        const bool valid = (n >= off);
        const int idx = valid ? (n - off) : 0;
        const size_t rb = (base_bn + idx) * (3 * PD);
        float4 k4 = *(const float4*)(qkv + rb + PD + col);
        float4 v4 = *(const float4*)(qkv + rb + 2 * PD + col);
        const float vm = valid ? 1.f : 0.f;
        const float dv = dot16(q4, k4) * vm;
        v4.x *= vm; v4.y *= vm; v4.z *= vm; v4.w *= vm;

        // user 1: (U1J[t], U1T[t])
        {
            const int j = U1J[t], tau = U1T[t];
            const float xx = dv + pos_bias[(j * 4 + tau) * PH + h];
            const float feat = (xx > 0.f ? xx : __expf(xx) - 1.f) + 1.f;
            const float coef = D4c[tau];
            const float w = g[j] * coef * feat;
            out4.x = fmaf(w, v4.x, out4.x);
            out4.y = fmaf(w, v4.y, out4.y);
            out4.z = fmaf(w, v4.z, out4.z);
            out4.w = fmaf(w, v4.w, out4.w);
            z = fmaf(g[j] * fabsf(coef), feat, z);
        }
        // user 2: (U2J[t], tau=1) if present
        if (U2J[t] >= 0) {
            const int j = U2J[t];
            const float xx = dv + pos_bias[(j * 4 + 1) * PH + h];
            const float feat = (xx > 0.f ? xx : __expf(xx) - 1.f) + 1.f;
            const float coef = D4c[1];
            const float w = g[j] * coef * feat;
            out4.x = fmaf(w, v4.x, out4.x);
            out4.y = fmaf(w, v4.y, out4.y);
            out4.z = fmaf(w, v4.z, out4.z);
            out4.w = fmaf(w, v4.w, out4.w);
            z = fmaf(g[j] * fabsf(coef), feat, z);
        }
    }

    // identity bypass
    const float bp = log1pf(__expf(identity_bypass[h]));  // softplus
    const float f0 = (dot0 > 0.f ? dot0 : __expf(dot0) - 1.f) + 1.f;
    const float w0 = bp * f0;
    out4.x = fmaf(w0, v04.x, out4.x);
    out4.y = fmaf(w0, v04.y, out4.y);
    out4.z = fmaf(w0, v04.z, out4.z);
    out4.w = fmaf(w0, v04.w, out4.w);
    z += w0;

    const float zi = 1.f / (z + 1e-6f);
    // gate-preact from separate buffer (short live range), fused sigmoid gate
    const float4 gp4 = *(const float4*)(gatep + (base_bn + n) * PD + col);
    ushort4 o;
    o.x = bf16bits(out4.x * zi / (1.f + __expf(-gp4.x)));
    o.y = bf16bits(out4.y * zi / (1.f + __expf(-gp4.y)));
    o.z = bf16bits(out4.z * zi / (1.f + __expf(-gp4.z)));
    o.w = bf16bits(out4.w * zi / (1.f + __expf(-gp4.w)));
    *(ushort4*)(gated + (base_bn + n) * PD + col) = o;
}

// ---------------- launch ----------------
extern "C" void kernel_launch(void* const* d_in, const int* in_sizes, int n_in,
                              void* d_out, int out_size, void* d_ws, size_t ws_size,
                              hipStream_t stream) {
    const float* x = (const float*)d_in[0];
    const float* W_qkv = (const float*)d_in[1];
    const float* b_qkv = (const float*)d_in[2];
    const float* W_out = (const float*)d_in[3];
    const float* b_out = (const float*)d_in[4];
    const float* W_gate = (const float*)d_in[5];
    const float* b_gate = (const float*)d_in[6];
    const float* scale_gain = (const float*)d_in[7];
    const float* W_qscale = (const float*)d_in[8];
    const float* identity_bypass = (const float*)d_in[9];
    const float* pos_bias = (const float*)d_in[10];
    float* out = (float*)d_out;

    const int M = PB * PN;  // 8192
    char* ws = (char*)d_ws;
    size_t off = 0;
    auto alloc = [&](size_t bytes) -> void* {
        void* p = ws + off;
        off += (bytes + 255) & ~(size_t)255;
        return p;
    };
    __hip_bfloat16* x_bf = (__hip_bfloat16*)alloc((size_t)M * PD * 2);
    __hip_bfloat16* wcomb_bf = (__hip_bfloat16*)alloc((size_t)4 * PD * PD * 2);
    __hip_bfloat16* wout_bf = (__hip_bfloat16*)alloc((size_t)PD * PD * 2);
    float* qkv = (float*)alloc((size_t)M * 3 * PD * 4);
    float* gate = (float*)alloc((size_t)M * PD * 4);
    __hip_bfloat16* gated = (__hip_bfloat16*)alloc((size_t)M * PD * 2);

    // casts
    cast_f32_to_bf16_v4<<<(M * PD / 4) / 256, 256, 0, stream>>>(
        (const float4*)x, (ushort4*)x_bf, M * PD / 4);
    cast_weights<<<(5 * PD * PD / 4) / 256, 256, 0, stream>>>(
        (const float4*)W_qkv, (const float4*)W_gate, (const float4*)W_out,
        (ushort4*)wcomb_bf, (ushort4*)wout_bf);

    // {qkv, gate} = x @ [W_qkv; W_gate]^T + {b_qkv, b_gate}
    gemm_bt128<<<dim3(4 * PD / GBN, M / GBM), 256, 0, stream>>>(
        x_bf, wcomb_bf, b_qkv, b_gate, 3 * PD, qkv, 3 * PD, gate, PD, PD);

    // attention + gating -> gated bf16 [8192, 1024]
    attn_kernel<<<(PB * PH * PN) / 16, 256, 0, stream>>>(
        qkv, scale_gain, W_qscale, identity_bypass, pos_bias, gate, gated);

    // out = gated @ W_out^T + b_out  -> fp32
    gemm_bt128<<<dim3(PD / GBN, M / GBM), 256, 0, stream>>>(
        gated, wout_bf, b_out, b_out, PD, out, PD, out, PD, PD);
}

// Round 10
// 394.660 us; speedup vs baseline: 1.7722x; 1.7722x over previous
//
#include <hip/hip_runtime.h>
#include <hip/hip_bf16.h>

// Problem constants
#define PB 4
#define PN 2048
#define PD 1024
#define PH 16
#define PHD 64
#define NSC 11

typedef __attribute__((ext_vector_type(8))) short short8;
typedef __attribute__((ext_vector_type(4))) float floatx4;

#define AS1 __attribute__((address_space(1)))
#define AS3 __attribute__((address_space(3)))

static __device__ __forceinline__ unsigned short bf16bits(float f) {
    __hip_bfloat16 h = __float2bfloat16(f);
    return __builtin_bit_cast(unsigned short, h);
}

// ---------------- cast kernels ----------------
__global__ void cast_f32_to_bf16_v4(const float4* __restrict__ in,
                                    ushort4* __restrict__ out, int n4) {
    int i = blockIdx.x * blockDim.x + threadIdx.x;
    if (i < n4) {
        float4 v = in[i];
        ushort4 o;
        o.x = bf16bits(v.x);
        o.y = bf16bits(v.y);
        o.z = bf16bits(v.z);
        o.w = bf16bits(v.w);
        out[i] = o;
    }
}

// casts W_qkv (3M) + W_gate (1M) into wcomb, W_out (1M) into wout
__global__ void cast_weights(const float4* __restrict__ wqkv,
                             const float4* __restrict__ wgate,
                             const float4* __restrict__ wout,
                             ushort4* __restrict__ wcomb,
                             ushort4* __restrict__ woutb) {
    int i = blockIdx.x * blockDim.x + threadIdx.x;  // 0 .. 5M/4
    const int QKV4 = 3 * PD * PD / 4;
    const int G4 = PD * PD / 4;
    float4 v;
    ushort4* dst;
    if (i < QKV4) {
        v = wqkv[i];
        dst = wcomb + i;
    } else if (i < QKV4 + G4) {
        v = wgate[i - QKV4];
        dst = wcomb + i;
    } else {
        v = wout[i - QKV4 - G4];
        dst = woutb + (i - QKV4 - G4);
    }
    ushort4 o;
    o.x = bf16bits(v.x);
    o.y = bf16bits(v.y);
    o.z = bf16bits(v.z);
    o.w = bf16bits(v.w);
    *dst = o;
}

// ---------------- GEMM 128x128: C = A @ B^T + bias, dual output ----------------
// A: [M,K] bf16 row-major; Bm: [Nn,K] bf16 row-major (W[out][in]).
// Columns < split  -> out1 (row stride N1), bias b1
// Columns >= split -> out2 (row stride N2), bias b2   (split is 128-aligned,
// so the branch is block-uniform)
#define GBM 128
#define GBN 128
#define GBK 64

__global__ __launch_bounds__(256) void gemm_bt128(
    const __hip_bfloat16* __restrict__ A,
    const __hip_bfloat16* __restrict__ Bm,
    const float* __restrict__ b1,
    const float* __restrict__ b2,
    int split,
    float* __restrict__ out1, int N1,
    float* __restrict__ out2, int N2,
    int K) {
    __shared__ alignas(16) __hip_bfloat16 sA[GBM * GBK];
    __shared__ alignas(16) __hip_bfloat16 sB[GBN * GBK];

    const int tid = threadIdx.x;
    const int lane = tid & 63;
    const int wave = tid >> 6;   // 0..3
    const int wy = wave >> 1;    // 0..1
    const int wx = wave & 1;     // 0..1

    // staging: each global_load_lds covers 8 rows x 64 elems (1 KiB)
    const int lrow8 = lane >> 3;                 // 0..7
    const int lchunk = lane & 7;                 // LDS chunk slot (8 elems)
    const int gchunk = lchunk ^ lrow8;           // global chunk fetched into slot

    const int r16 = lane & 15;
    const int qd = lane >> 4;
    const int sw = r16 & 7;  // reader swizzle key

    floatx4 acc[4][4];
#pragma unroll
    for (int i = 0; i < 4; i++)
#pragma unroll
        for (int j = 0; j < 4; j++) acc[i][j] = (floatx4){0.f, 0.f, 0.f, 0.f};

    const size_t arow0 = (size_t)blockIdx.y * GBM;
    const size_t brow0 = (size_t)blockIdx.x * GBN;

    for (int k0 = 0; k0 < K; k0 += GBK) {
        __syncthreads();  // previous ds_reads done before overwrite
#pragma unroll
        for (int half = 0; half < 4; half++) {
            const int rbase = wave * 8 + half * 32;  // wave-uniform
            const __hip_bfloat16* gA =
                A + (arow0 + rbase + lrow8) * K + k0 + gchunk * 8;
            __builtin_amdgcn_global_load_lds(
                (const AS1 unsigned int*)(const void*)gA,
                (AS3 unsigned int*)(void*)(sA + rbase * GBK), 16, 0, 0);
            const __hip_bfloat16* gB =
                Bm + (brow0 + rbase + lrow8) * K + k0 + gchunk * 8;
            __builtin_amdgcn_global_load_lds(
                (const AS1 unsigned int*)(const void*)gB,
                (AS3 unsigned int*)(void*)(sB + rbase * GBK), 16, 0, 0);
        }
        __syncthreads();  // drain staging

#pragma unroll
        for (int kk = 0; kk < 2; kk++) {
            short8 af[4], bf[4];
            const int cs = (qd + 4 * kk);
#pragma unroll
            for (int i = 0; i < 4; i++)
                af[i] = *(const short8*)(sA + (wy * 64 + i * 16 + r16) * GBK +
                                         ((cs ^ sw) * 8));
#pragma unroll
            for (int j = 0; j < 4; j++)
                bf[j] = *(const short8*)(sB + (wx * 64 + j * 16 + r16) * GBK +
                                         ((cs ^ sw) * 8));
#pragma unroll
            for (int i = 0; i < 4; i++)
#pragma unroll
                for (int j = 0; j < 4; j++)
                    acc[i][j] = __builtin_amdgcn_mfma_f32_16x16x32_bf16(
                        af[i], bf[j], acc[i][j], 0, 0, 0);
        }
    }

#pragma unroll
    for (int i = 0; i < 4; i++) {
#pragma unroll
        for (int j = 0; j < 4; j++) {
            const int colb = (int)brow0 + wx * 64 + j * 16 + r16;
            const bool first = colb < split;
            const float bb = first ? b1[colb] : b2[colb - split];
            float* dst = first ? out1 : out2;
            const int nn = first ? N1 : N2;
            const int cc = first ? colb : colb - split;
#pragma unroll
            for (int e = 0; e < 4; e++) {
                const size_t row = arow0 + wy * 64 + i * 16 + qd * 4 + e;
                dst[row * (size_t)nn + cc] = acc[i][j][e] + bb;
            }
        }
    }
}

// ---------------- attention + gating kernel ----------------
// Layout: 1 wave = 4 consecutive n positions; 16 lanes x float4 per position.
// qkv: [B, N, 3D] fp32 (EXACT R6 layout); gatep: [B, N, D] fp32 (separate).
// Writes gated bf16 [B,N,D]: bf16((out/z) * sigmoid(gate_preact)).
// NOTE: no min-waves launch_bounds — R9's (256,6) forced VGPR=40 and spilled
// (WRITE_SIZE 16->966 MB). Compiler-chosen allocation (R6: 68 VGPR) is right.

__device__ __constant__ const int OFFS[21] = {1, 2, 3, 4, 6, 8, 12, 16, 24, 32, 48,
                                              64, 96, 128, 192, 256, 384, 512, 768, 1024, 1536};
__device__ __constant__ const int U1J[21] = {0, 0, 0, 1, 1, 2, 2, 3, 3, 4, 4,
                                             5, 5, 6, 6, 7, 7, 8, 8, 9, 9};
__device__ __constant__ const int U1T[21] = {1, 2, 3, 2, 3, 2, 3, 2, 3, 2, 3,
                                             2, 3, 2, 3, 2, 3, 2, 3, 2, 3};
// second user j (tau is always 1); -1 = none
__device__ __constant__ const int U2J[21] = {-1, 1, -1, 2, -1, 3, -1, 4, -1, 5, -1,
                                             6, -1, 7, -1, 8, -1, 9, -1, 10, -1};

static __device__ __forceinline__ float red16(float s) {
    // sum across each 16-lane DPP row via rotations; all lanes get the sum
    int t;
    t = __builtin_amdgcn_update_dpp(0, __builtin_bit_cast(int, s), 0x121, 0xF, 0xF, true);
    s += __builtin_bit_cast(float, t);  // row_ror:1
    t = __builtin_amdgcn_update_dpp(0, __builtin_bit_cast(int, s), 0x122, 0xF, 0xF, true);
    s += __builtin_bit_cast(float, t);  // row_ror:2
    t = __builtin_amdgcn_update_dpp(0, __builtin_bit_cast(int, s), 0x124, 0xF, 0xF, true);
    s += __builtin_bit_cast(float, t);  // row_ror:4
    t = __builtin_amdgcn_update_dpp(0, __builtin_bit_cast(int, s), 0x128, 0xF, 0xF, true);
    s += __builtin_bit_cast(float, t);  // row_ror:8
    return s;
}

__global__ __launch_bounds__(256) void attn_kernel(
    const float* __restrict__ qkv,
    const float* __restrict__ scale_gain,       // [11,16]
    const float* __restrict__ W_qscale,         // [11,64]
    const float* __restrict__ identity_bypass,  // [16]
    const float* __restrict__ pos_bias,         // [44,16]
    const float* __restrict__ gatep,            // [B,N,D] gate preact
    __hip_bfloat16* __restrict__ gated) {
    const int lane = threadIdx.x & 63;
    const int p = lane >> 4;   // position within wave, 0..3
    const int l = lane & 15;   // d-chunk, 0..15

    const int flat = (blockIdx.x * 4 + (threadIdx.x >> 6)) * 4;  // first n of wave
    const int n = (flat & (PN - 1)) + p;
    const int h = (flat >> 11) & (PH - 1);
    const int b = flat >> 15;

    const size_t base_bn = (size_t)b * PN;
    const int col = h * PHD + l * 4;

    const float4 q4 = *(const float4*)(qkv + (base_bn + n) * (3 * PD) + col);
    const float4 k04 = *(const float4*)(qkv + (base_bn + n) * (3 * PD) + PD + col);
    const float4 v04 = *(const float4*)(qkv + (base_bn + n) * (3 * PD) + 2 * PD + col);

    auto dot16 = [](float4 a, float4 b) {
        float s = a.x * b.x;
        s = fmaf(a.y, b.y, s);
        s = fmaf(a.z, b.z, s);
        s = fmaf(a.w, b.w, s);
        return red16(s);
    };

    const float dot0 = dot16(q4, k04);

    // gains = softmax(q @ W_qscale^T + scale_gain[:,h]) over 11 scales
    float g[NSC];
    float mx = -1e30f;
#pragma unroll
    for (int s = 0; s < NSC; s++) {
        const float4 w4 = *(const float4*)(W_qscale + s * PHD + l * 4);
        g[s] = dot16(q4, w4) + scale_gain[s * PH + h];
        mx = fmaxf(mx, g[s]);
    }
    float ssum = 0.f;
#pragma unroll
    for (int s = 0; s < NSC; s++) {
        g[s] = __expf(g[s] - mx);
        ssum += g[s];
    }
    const float inv = 1.f / ssum;
#pragma unroll
    for (int s = 0; s < NSC; s++) g[s] *= inv;

    const float D4c[4] = {0.4829629131445341f, 0.8365163037378079f,
                          0.2241438680420134f, -0.1294095225512604f};

    float4 out4 = {0.f, 0.f, 0.f, 0.f};
    float z = 0.f;

    // offset-0 taps: tau=0 for every scale j
#pragma unroll
    for (int j = 0; j < NSC; j++) {
        const float xx = dot0 + pos_bias[(j * 4) * PH + h];
        const float feat = (xx > 0.f ? xx : __expf(xx) - 1.f) + 1.f;
        const float w = g[j] * D4c[0] * feat;
        out4.x = fmaf(w, v04.x, out4.x);
        out4.y = fmaf(w, v04.y, out4.y);
        out4.z = fmaf(w, v04.z, out4.z);
        out4.w = fmaf(w, v04.w, out4.w);
        z = fmaf(g[j] * D4c[0], feat, z);  // |coef| == coef for tau=0
    }

    // distinct nonzero offsets (each used by 1-2 taps)
#pragma unroll
    for (int t = 0; t < 21; t++) {
        const int off = OFFS[t];
        const bool valid = (n >= off);
        const int idx = valid ? (n - off) : 0;
        const size_t rb = (base_bn + idx) * (3 * PD);
        float4 k4 = *(const float4*)(qkv + rb + PD + col);
        float4 v4 = *(const float4*)(qkv + rb + 2 * PD + col);
        const float vm = valid ? 1.f : 0.f;
        const float dv = dot16(q4, k4) * vm;
        v4.x *= vm; v4.y *= vm; v4.z *= vm; v4.w *= vm;

        // user 1: (U1J[t], U1T[t])
        {
            const int j = U1J[t], tau = U1T[t];
            const float xx = dv + pos_bias[(j * 4 + tau) * PH + h];
            const float feat = (xx > 0.f ? xx : __expf(xx) - 1.f) + 1.f;
            const float coef = D4c[tau];
            const float w = g[j] * coef * feat;
            out4.x = fmaf(w, v4.x, out4.x);
            out4.y = fmaf(w, v4.y, out4.y);
            out4.z = fmaf(w, v4.z, out4.z);
            out4.w = fmaf(w, v4.w, out4.w);
            z = fmaf(g[j] * fabsf(coef), feat, z);
        }
        // user 2: (U2J[t], tau=1) if present
        if (U2J[t] >= 0) {
            const int j = U2J[t];
            const float xx = dv + pos_bias[(j * 4 + 1) * PH + h];
            const float feat = (xx > 0.f ? xx : __expf(xx) - 1.f) + 1.f;
            const float coef = D4c[1];
            const float w = g[j] * coef * feat;
            out4.x = fmaf(w, v4.x, out4.x);
            out4.y = fmaf(w, v4.y, out4.y);
            out4.z = fmaf(w, v4.z, out4.z);
            out4.w = fmaf(w, v4.w, out4.w);
            z = fmaf(g[j] * fabsf(coef), feat, z);
        }
    }

    // identity bypass
    const float bp = log1pf(__expf(identity_bypass[h]));  // softplus
    const float f0 = (dot0 > 0.f ? dot0 : __expf(dot0) - 1.f) + 1.f;
    const float w0 = bp * f0;
    out4.x = fmaf(w0, v04.x, out4.x);
    out4.y = fmaf(w0, v04.y, out4.y);
    out4.z = fmaf(w0, v04.z, out4.z);
    out4.w = fmaf(w0, v04.w, out4.w);
    z += w0;

    const float zi = 1.f / (z + 1e-6f);
    // gate-preact from separate buffer (short live range), fused sigmoid gate
    const float4 gp4 = *(const float4*)(gatep + (base_bn + n) * PD + col);
    ushort4 o;
    o.x = bf16bits(out4.x * zi / (1.f + __expf(-gp4.x)));
    o.y = bf16bits(out4.y * zi / (1.f + __expf(-gp4.y)));
    o.z = bf16bits(out4.z * zi / (1.f + __expf(-gp4.z)));
    o.w = bf16bits(out4.w * zi / (1.f + __expf(-gp4.w)));
    *(ushort4*)(gated + (base_bn + n) * PD + col) = o;
}

// ---------------- launch ----------------
extern "C" void kernel_launch(void* const* d_in, const int* in_sizes, int n_in,
                              void* d_out, int out_size, void* d_ws, size_t ws_size,
                              hipStream_t stream) {
    const float* x = (const float*)d_in[0];
    const float* W_qkv = (const float*)d_in[1];
    const float* b_qkv = (const float*)d_in[2];
    const float* W_out = (const float*)d_in[3];
    const float* b_out = (const float*)d_in[4];
    const float* W_gate = (const float*)d_in[5];
    const float* b_gate = (const float*)d_in[6];
    const float* scale_gain = (const float*)d_in[7];
    const float* W_qscale = (const float*)d_in[8];
    const float* identity_bypass = (const float*)d_in[9];
    const float* pos_bias = (const float*)d_in[10];
    float* out = (float*)d_out;

    const int M = PB * PN;  // 8192
    char* ws = (char*)d_ws;
    size_t off = 0;
    auto alloc = [&](size_t bytes) -> void* {
        void* p = ws + off;
        off += (bytes + 255) & ~(size_t)255;
        return p;
    };
    __hip_bfloat16* x_bf = (__hip_bfloat16*)alloc((size_t)M * PD * 2);
    __hip_bfloat16* wcomb_bf = (__hip_bfloat16*)alloc((size_t)4 * PD * PD * 2);
    __hip_bfloat16* wout_bf = (__hip_bfloat16*)alloc((size_t)PD * PD * 2);
    float* qkv = (float*)alloc((size_t)M * 3 * PD * 4);
    float* gate = (float*)alloc((size_t)M * PD * 4);
    __hip_bfloat16* gated = (__hip_bfloat16*)alloc((size_t)M * PD * 2);

    // casts
    cast_f32_to_bf16_v4<<<(M * PD / 4) / 256, 256, 0, stream>>>(
        (const float4*)x, (ushort4*)x_bf, M * PD / 4);
    cast_weights<<<(5 * PD * PD / 4) / 256, 256, 0, stream>>>(
        (const float4*)W_qkv, (const float4*)W_gate, (const float4*)W_out,
        (ushort4*)wcomb_bf, (ushort4*)wout_bf);

    // {qkv, gate} = x @ [W_qkv; W_gate]^T + {b_qkv, b_gate}
    gemm_bt128<<<dim3(4 * PD / GBN, M / GBM), 256, 0, stream>>>(
        x_bf, wcomb_bf, b_qkv, b_gate, 3 * PD, qkv, 3 * PD, gate, PD, PD);

    // attention + gating -> gated bf16 [8192, 1024]
    attn_kernel<<<(PB * PH * PN) / 16, 256, 0, stream>>>(
        qkv, scale_gain, W_qscale, identity_bypass, pos_bias, gate, gated);

    // out = gated @ W_out^T + b_out  -> fp32
    gemm_bt128<<<dim3(PD / GBN, M / GBM), 256, 0, stream>>>(
        gated, wout_bf, b_out, b_out, PD, out, PD, out, PD, PD);
}

// Round 11
// 333.390 us; speedup vs baseline: 2.0979x; 1.1838x over previous
//
#include <hip/hip_runtime.h>
#include <hip/hip_bf16.h>

// Problem constants
#define PB 4
#define PN 2048
#define PD 1024
#define PH 16
#define PHD 64
#define NSC 11

typedef __attribute__((ext_vector_type(8))) short short8;
typedef __attribute__((ext_vector_type(4))) float floatx4;

#define AS1 __attribute__((address_space(1)))
#define AS3 __attribute__((address_space(3)))

static __device__ __forceinline__ unsigned short bf16bits(float f) {
    __hip_bfloat16 h = __float2bfloat16(f);
    return __builtin_bit_cast(unsigned short, h);
}

// ---------------- cast kernels ----------------
__global__ void cast_f32_to_bf16_v4(const float4* __restrict__ in,
                                    ushort4* __restrict__ out, int n4) {
    int i = blockIdx.x * blockDim.x + threadIdx.x;
    if (i < n4) {
        float4 v = in[i];
        ushort4 o;
        o.x = bf16bits(v.x);
        o.y = bf16bits(v.y);
        o.z = bf16bits(v.z);
        o.w = bf16bits(v.w);
        out[i] = o;
    }
}

// casts W_qkv (3M) + W_gate (1M) into wcomb, W_out (1M) into wout
__global__ void cast_weights(const float4* __restrict__ wqkv,
                             const float4* __restrict__ wgate,
                             const float4* __restrict__ wout,
                             ushort4* __restrict__ wcomb,
                             ushort4* __restrict__ woutb) {
    int i = blockIdx.x * blockDim.x + threadIdx.x;  // 0 .. 5M/4
    const int QKV4 = 3 * PD * PD / 4;
    const int G4 = PD * PD / 4;
    float4 v;
    ushort4* dst;
    if (i < QKV4) {
        v = wqkv[i];
        dst = wcomb + i;
    } else if (i < QKV4 + G4) {
        v = wgate[i - QKV4];
        dst = wcomb + i;
    } else {
        v = wout[i - QKV4 - G4];
        dst = woutb + (i - QKV4 - G4);
    }
    ushort4 o;
    o.x = bf16bits(v.x);
    o.y = bf16bits(v.y);
    o.z = bf16bits(v.z);
    o.w = bf16bits(v.w);
    *dst = o;
}

// gated = bf16(att * sigmoid(gatep)) — pure HBM stream
__global__ void gate_mul(const float4* __restrict__ att,
                         const float4* __restrict__ gatep,
                         ushort4* __restrict__ gated, int n4) {
    int i = blockIdx.x * blockDim.x + threadIdx.x;
    if (i < n4) {
        float4 a = att[i];
        float4 gp = gatep[i];
        ushort4 o;
        o.x = bf16bits(a.x / (1.f + __expf(-gp.x)));
        o.y = bf16bits(a.y / (1.f + __expf(-gp.y)));
        o.z = bf16bits(a.z / (1.f + __expf(-gp.z)));
        o.w = bf16bits(a.w / (1.f + __expf(-gp.w)));
        gated[i] = o;
    }
}

// ---------------- GEMM 128x128: C = A @ B^T + bias, dual output ----------------
// A: [M,K] bf16 row-major; Bm: [Nn,K] bf16 row-major (W[out][in]).
// Columns < split  -> out1 (row stride N1), bias b1
// Columns >= split -> out2 (row stride N2), bias b2   (split is 128-aligned,
// so the branch is block-uniform)
#define GBM 128
#define GBN 128
#define GBK 64

__global__ __launch_bounds__(256) void gemm_bt128(
    const __hip_bfloat16* __restrict__ A,
    const __hip_bfloat16* __restrict__ Bm,
    const float* __restrict__ b1,
    const float* __restrict__ b2,
    int split,
    float* __restrict__ out1, int N1,
    float* __restrict__ out2, int N2,
    int K) {
    __shared__ alignas(16) __hip_bfloat16 sA[GBM * GBK];
    __shared__ alignas(16) __hip_bfloat16 sB[GBN * GBK];

    const int tid = threadIdx.x;
    const int lane = tid & 63;
    const int wave = tid >> 6;   // 0..3
    const int wy = wave >> 1;    // 0..1
    const int wx = wave & 1;     // 0..1

    // staging: each global_load_lds covers 8 rows x 64 elems (1 KiB)
    const int lrow8 = lane >> 3;                 // 0..7
    const int lchunk = lane & 7;                 // LDS chunk slot (8 elems)
    const int gchunk = lchunk ^ lrow8;           // global chunk fetched into slot

    const int r16 = lane & 15;
    const int qd = lane >> 4;
    const int sw = r16 & 7;  // reader swizzle key

    floatx4 acc[4][4];
#pragma unroll
    for (int i = 0; i < 4; i++)
#pragma unroll
        for (int j = 0; j < 4; j++) acc[i][j] = (floatx4){0.f, 0.f, 0.f, 0.f};

    const size_t arow0 = (size_t)blockIdx.y * GBM;
    const size_t brow0 = (size_t)blockIdx.x * GBN;

    for (int k0 = 0; k0 < K; k0 += GBK) {
        __syncthreads();  // previous ds_reads done before overwrite
#pragma unroll
        for (int half = 0; half < 4; half++) {
            const int rbase = wave * 8 + half * 32;  // wave-uniform
            const __hip_bfloat16* gA =
                A + (arow0 + rbase + lrow8) * K + k0 + gchunk * 8;
            __builtin_amdgcn_global_load_lds(
                (const AS1 unsigned int*)(const void*)gA,
                (AS3 unsigned int*)(void*)(sA + rbase * GBK), 16, 0, 0);
            const __hip_bfloat16* gB =
                Bm + (brow0 + rbase + lrow8) * K + k0 + gchunk * 8;
            __builtin_amdgcn_global_load_lds(
                (const AS1 unsigned int*)(const void*)gB,
                (AS3 unsigned int*)(void*)(sB + rbase * GBK), 16, 0, 0);
        }
        __syncthreads();  // drain staging

#pragma unroll
        for (int kk = 0; kk < 2; kk++) {
            short8 af[4], bf[4];
            const int cs = (qd + 4 * kk);
#pragma unroll
            for (int i = 0; i < 4; i++)
                af[i] = *(const short8*)(sA + (wy * 64 + i * 16 + r16) * GBK +
                                         ((cs ^ sw) * 8));
#pragma unroll
            for (int j = 0; j < 4; j++)
                bf[j] = *(const short8*)(sB + (wx * 64 + j * 16 + r16) * GBK +
                                         ((cs ^ sw) * 8));
#pragma unroll
            for (int i = 0; i < 4; i++)
#pragma unroll
                for (int j = 0; j < 4; j++)
                    acc[i][j] = __builtin_amdgcn_mfma_f32_16x16x32_bf16(
                        af[i], bf[j], acc[i][j], 0, 0, 0);
        }
    }

#pragma unroll
    for (int i = 0; i < 4; i++) {
#pragma unroll
        for (int j = 0; j < 4; j++) {
            const int colb = (int)brow0 + wx * 64 + j * 16 + r16;
            const bool first = colb < split;
            const float bb = first ? b1[colb] : b2[colb - split];
            float* dst = first ? out1 : out2;
            const int nn = first ? N1 : N2;
            const int cc = first ? colb : colb - split;
#pragma unroll
            for (int e = 0; e < 4; e++) {
                const size_t row = arow0 + wy * 64 + i * 16 + qd * 4 + e;
                dst[row * (size_t)nn + cc] = acc[i][j][e] + bb;
            }
        }
    }
}

// ---------------- attention kernel (EXACT R6 body: fp32 out, no gate) ------
// Layout: 1 wave = 4 consecutive n positions; 16 lanes x float4 per position.
// qkv: [B, N, 3D] fp32 (q | k | v chunks of D); att: [B, N, D] fp32.
// R6-proven: 68 VGPR, no gate fusion — every gate-fused variant compiled to
// 100-104 VGPR and lost 2 waves/SIMD (latency-bound kernel -> 1.7x slower).

__device__ __constant__ const int OFFS[21] = {1, 2, 3, 4, 6, 8, 12, 16, 24, 32, 48,
                                              64, 96, 128, 192, 256, 384, 512, 768, 1024, 1536};
__device__ __constant__ const int U1J[21] = {0, 0, 0, 1, 1, 2, 2, 3, 3, 4, 4,
                                             5, 5, 6, 6, 7, 7, 8, 8, 9, 9};
__device__ __constant__ const int U1T[21] = {1, 2, 3, 2, 3, 2, 3, 2, 3, 2, 3,
                                             2, 3, 2, 3, 2, 3, 2, 3, 2, 3};
// second user j (tau is always 1); -1 = none
__device__ __constant__ const int U2J[21] = {-1, 1, -1, 2, -1, 3, -1, 4, -1, 5, -1,
                                             6, -1, 7, -1, 8, -1, 9, -1, 10, -1};

static __device__ __forceinline__ float red16(float s) {
    // sum across each 16-lane DPP row via rotations; all lanes get the sum
    int t;
    t = __builtin_amdgcn_update_dpp(0, __builtin_bit_cast(int, s), 0x121, 0xF, 0xF, true);
    s += __builtin_bit_cast(float, t);  // row_ror:1
    t = __builtin_amdgcn_update_dpp(0, __builtin_bit_cast(int, s), 0x122, 0xF, 0xF, true);
    s += __builtin_bit_cast(float, t);  // row_ror:2
    t = __builtin_amdgcn_update_dpp(0, __builtin_bit_cast(int, s), 0x124, 0xF, 0xF, true);
    s += __builtin_bit_cast(float, t);  // row_ror:4
    t = __builtin_amdgcn_update_dpp(0, __builtin_bit_cast(int, s), 0x128, 0xF, 0xF, true);
    s += __builtin_bit_cast(float, t);  // row_ror:8
    return s;
}

__global__ __launch_bounds__(256) void attn_kernel(
    const float* __restrict__ qkv,
    const float* __restrict__ scale_gain,       // [11,16]
    const float* __restrict__ W_qscale,         // [11,64]
    const float* __restrict__ identity_bypass,  // [16]
    const float* __restrict__ pos_bias,         // [44,16]
    float* __restrict__ att) {
    const int lane = threadIdx.x & 63;
    const int p = lane >> 4;   // position within wave, 0..3
    const int l = lane & 15;   // d-chunk, 0..15

    const int flat = (blockIdx.x * 4 + (threadIdx.x >> 6)) * 4;  // first n of wave
    const int n = (flat & (PN - 1)) + p;
    const int h = (flat >> 11) & (PH - 1);
    const int b = flat >> 15;

    const size_t base_bn = (size_t)b * PN;
    const int col = h * PHD + l * 4;

    const float4 q4 = *(const float4*)(qkv + (base_bn + n) * (3 * PD) + col);
    const float4 k04 = *(const float4*)(qkv + (base_bn + n) * (3 * PD) + PD + col);
    const float4 v04 = *(const float4*)(qkv + (base_bn + n) * (3 * PD) + 2 * PD + col);

    auto dot16 = [](float4 a, float4 b) {
        float s = a.x * b.x;
        s = fmaf(a.y, b.y, s);
        s = fmaf(a.z, b.z, s);
        s = fmaf(a.w, b.w, s);
        return red16(s);
    };

    const float dot0 = dot16(q4, k04);

    // gains = softmax(q @ W_qscale^T + scale_gain[:,h]) over 11 scales
    float g[NSC];
    float mx = -1e30f;
#pragma unroll
    for (int s = 0; s < NSC; s++) {
        const float4 w4 = *(const float4*)(W_qscale + s * PHD + l * 4);
        g[s] = dot16(q4, w4) + scale_gain[s * PH + h];
        mx = fmaxf(mx, g[s]);
    }
    float ssum = 0.f;
#pragma unroll
    for (int s = 0; s < NSC; s++) {
        g[s] = __expf(g[s] - mx);
        ssum += g[s];
    }
    const float inv = 1.f / ssum;
#pragma unroll
    for (int s = 0; s < NSC; s++) g[s] *= inv;

    const float D4c[4] = {0.4829629131445341f, 0.8365163037378079f,
                          0.2241438680420134f, -0.1294095225512604f};

    float4 out4 = {0.f, 0.f, 0.f, 0.f};
    float z = 0.f;

    // offset-0 taps: tau=0 for every scale j
#pragma unroll
    for (int j = 0; j < NSC; j++) {
        const float xx = dot0 + pos_bias[(j * 4) * PH + h];
        const float feat = (xx > 0.f ? xx : __expf(xx) - 1.f) + 1.f;
        const float w = g[j] * D4c[0] * feat;
        out4.x = fmaf(w, v04.x, out4.x);
        out4.y = fmaf(w, v04.y, out4.y);
        out4.z = fmaf(w, v04.z, out4.z);
        out4.w = fmaf(w, v04.w, out4.w);
        z = fmaf(g[j] * D4c[0], feat, z);  // |coef| == coef for tau=0
    }

    // distinct nonzero offsets (each used by 1-2 taps)
#pragma unroll
    for (int t = 0; t < 21; t++) {
        const int off = OFFS[t];
        const bool valid = (n >= off);
        const int idx = valid ? (n - off) : 0;
        const size_t rb = (base_bn + idx) * (3 * PD);
        float4 k4 = *(const float4*)(qkv + rb + PD + col);
        float4 v4 = *(const float4*)(qkv + rb + 2 * PD + col);
        const float vm = valid ? 1.f : 0.f;
        const float dv = dot16(q4, k4) * vm;
        v4.x *= vm; v4.y *= vm; v4.z *= vm; v4.w *= vm;

        // user 1: (U1J[t], U1T[t])
        {
            const int j = U1J[t], tau = U1T[t];
            const float xx = dv + pos_bias[(j * 4 + tau) * PH + h];
            const float feat = (xx > 0.f ? xx : __expf(xx) - 1.f) + 1.f;
            const float coef = D4c[tau];
            const float w = g[j] * coef * feat;
            out4.x = fmaf(w, v4.x, out4.x);
            out4.y = fmaf(w, v4.y, out4.y);
            out4.z = fmaf(w, v4.z, out4.z);
            out4.w = fmaf(w, v4.w, out4.w);
            z = fmaf(g[j] * fabsf(coef), feat, z);
        }
        // user 2: (U2J[t], tau=1) if present
        if (U2J[t] >= 0) {
            const int j = U2J[t];
            const float xx = dv + pos_bias[(j * 4 + 1) * PH + h];
            const float feat = (xx > 0.f ? xx : __expf(xx) - 1.f) + 1.f;
            const float coef = D4c[1];
            const float w = g[j] * coef * feat;
            out4.x = fmaf(w, v4.x, out4.x);
            out4.y = fmaf(w, v4.y, out4.y);
            out4.z = fmaf(w, v4.z, out4.z);
            out4.w = fmaf(w, v4.w, out4.w);
            z = fmaf(g[j] * fabsf(coef), feat, z);
        }
    }

    // identity bypass
    const float bp = log1pf(__expf(identity_bypass[h]));  // softplus
    const float f0 = (dot0 > 0.f ? dot0 : __expf(dot0) - 1.f) + 1.f;
    const float w0 = bp * f0;
    out4.x = fmaf(w0, v04.x, out4.x);
    out4.y = fmaf(w0, v04.y, out4.y);
    out4.z = fmaf(w0, v04.z, out4.z);
    out4.w = fmaf(w0, v04.w, out4.w);
    z += w0;

    const float zi = 1.f / (z + 1e-6f);
    float4 o;
    o.x = out4.x * zi; o.y = out4.y * zi; o.z = out4.z * zi; o.w = out4.w * zi;
    *(float4*)(att + (base_bn + n) * PD + col) = o;
}

// ---------------- launch ----------------
extern "C" void kernel_launch(void* const* d_in, const int* in_sizes, int n_in,
                              void* d_out, int out_size, void* d_ws, size_t ws_size,
                              hipStream_t stream) {
    const float* x = (const float*)d_in[0];
    const float* W_qkv = (const float*)d_in[1];
    const float* b_qkv = (const float*)d_in[2];
    const float* W_out = (const float*)d_in[3];
    const float* b_out = (const float*)d_in[4];
    const float* W_gate = (const float*)d_in[5];
    const float* b_gate = (const float*)d_in[6];
    const float* scale_gain = (const float*)d_in[7];
    const float* W_qscale = (const float*)d_in[8];
    const float* identity_bypass = (const float*)d_in[9];
    const float* pos_bias = (const float*)d_in[10];
    float* out = (float*)d_out;

    const int M = PB * PN;  // 8192
    char* ws = (char*)d_ws;
    size_t off = 0;
    auto alloc = [&](size_t bytes) -> void* {
        void* p = ws + off;
        off += (bytes + 255) & ~(size_t)255;
        return p;
    };
    __hip_bfloat16* x_bf = (__hip_bfloat16*)alloc((size_t)M * PD * 2);
    __hip_bfloat16* wcomb_bf = (__hip_bfloat16*)alloc((size_t)4 * PD * PD * 2);
    __hip_bfloat16* wout_bf = (__hip_bfloat16*)alloc((size_t)PD * PD * 2);
    float* qkv = (float*)alloc((size_t)M * 3 * PD * 4);
    float* gate = (float*)alloc((size_t)M * PD * 4);
    float* att = (float*)alloc((size_t)M * PD * 4);
    __hip_bfloat16* gated = (__hip_bfloat16*)alloc((size_t)M * PD * 2);

    // casts
    cast_f32_to_bf16_v4<<<(M * PD / 4) / 256, 256, 0, stream>>>(
        (const float4*)x, (ushort4*)x_bf, M * PD / 4);
    cast_weights<<<(5 * PD * PD / 4) / 256, 256, 0, stream>>>(
        (const float4*)W_qkv, (const float4*)W_gate, (const float4*)W_out,
        (ushort4*)wcomb_bf, (ushort4*)wout_bf);

    // {qkv, gate} = x @ [W_qkv; W_gate]^T + {b_qkv, b_gate}
    gemm_bt128<<<dim3(4 * PD / GBN, M / GBM), 256, 0, stream>>>(
        x_bf, wcomb_bf, b_qkv, b_gate, 3 * PD, qkv, 3 * PD, gate, PD, PD);

    // attention -> att fp32 [8192, 1024]
    attn_kernel<<<(PB * PH * PN) / 16, 256, 0, stream>>>(
        qkv, scale_gain, W_qscale, identity_bypass, pos_bias, att);

    // gated = bf16(att * sigmoid(gate))  (elementwise, HBM-bound ~12 us)
    gate_mul<<<(M * PD / 4) / 256, 256, 0, stream>>>(
        (const float4*)att, (const float4*)gate, (ushort4*)gated, M * PD / 4);

    // out = gated @ W_out^T + b_out  -> fp32
    gemm_bt128<<<dim3(PD / GBN, M / GBM), 256, 0, stream>>>(
        gated, wout_bf, b_out, b_out, PD, out, PD, out, PD, PD);
}